// Round 5
// baseline (470.862 us; speedup 1.0000x reference)
//
#include <hip/hip_runtime.h>

#define N_TOT 65536
#define C_DIM 128
#define K_CB  1024
#define BN  128    // z-rows per block
#define BKT 128    // codes per K-tile
#define LDSS 36    // LDS row stride (floats): shift 4 banks/row -> <=2-way (free)
#define NROW_B 4
#define NBLK_B (N_TOT / NROW_B)

// ---------------------------------------------------------------------------
// Kernel 1: cb_sq[k] = fl32( fp64 sum c^2 ) — one wave per code row.
// ---------------------------------------------------------------------------
__global__ __launch_bounds__(256) void cbsq_kernel(const float* __restrict__ cb,
                                                   float* __restrict__ out) {
  int w = threadIdx.x >> 6, lane = threadIdx.x & 63;
  int r = blockIdx.x * 4 + w;
  float2 v = reinterpret_cast<const float2*>(cb + (size_t)r * C_DIM)[lane];
  double s = (double)v.x * (double)v.x + (double)v.y * (double)v.y;
#pragma unroll
  for (int off = 32; off >= 1; off >>= 1) s += __shfl_xor(s, off, 64);
  if (lane == 0) out[r] = (float)s;
}

// ---------------------------------------------------------------------------
// Kernel 2: fp32 filter, per-row TOP-4 candidates.
// Block 256 thr; output tile 128 rows x 128 codes; per-thread 8x8.
// C staged in 32-float chunks -> LDS bytes/FMA = 1.0 (was 2.0 in R4: the
// R4 binder was the LDS data path at 256 B/cyc demand vs ~100 supply).
// ---------------------------------------------------------------------------
__global__ __launch_bounds__(256, 2) void dist_topk_kernel(
    const float* __restrict__ ze, const float* __restrict__ cb,
    const float* __restrict__ cbsq, ushort* __restrict__ cand) {
  __shared__ float smem[2 * BN * LDSS];   // 36864 B total
  float (*zeS)[LDSS] = reinterpret_cast<float(*)[LDSS]>(smem);
  float (*cbS)[LDSS] = reinterpret_cast<float(*)[LDSS]>(smem + BN * LDSS);

  const int tid = threadIdx.x;
  const int tx = tid & 15, ty = tid >> 4;
  const int rowbase = blockIdx.x * BN;

  float b1k[8], b2k[8];
  int b1i[8], b2i[8];
#pragma unroll
  for (int r = 0; r < 8; ++r) { b1k[r] = 3e38f; b2k[r] = 3e38f; b1i[r] = 0; b2i[r] = 0; }

  for (int kc = 0; kc < K_CB / BKT; ++kc) {
    float acc[8][8];
#pragma unroll
    for (int r = 0; r < 8; ++r)
#pragma unroll
      for (int j = 0; j < 8; ++j) acc[r][j] = 0.f;

    for (int cc = 0; cc < 4; ++cc) {        // 4 chunks of 32 C-floats
      __syncthreads();                       // prev chunk fully consumed
#pragma unroll
      for (int i = 0; i < 4; ++i) {          // stage: 1024 float4 per tile
        int fid = i * 256 + tid;
        int row = fid >> 3, c4 = fid & 7;    // 128 rows x 8 float4
        float4 vz = reinterpret_cast<const float4*>(ze)[(size_t)(rowbase + row) * 32 + cc * 8 + c4];
        *reinterpret_cast<float4*>(&zeS[row][c4 * 4]) = vz;
        float4 vc = reinterpret_cast<const float4*>(cb)[(size_t)(kc * BKT + row) * 32 + cc * 8 + c4];
        *reinterpret_cast<float4*>(&cbS[row][c4 * 4]) = vc;
      }
      __syncthreads();

#pragma unroll 2
      for (int c4 = 0; c4 < 8; ++c4) {
        float4 cf[8];
#pragma unroll
        for (int j = 0; j < 8; ++j)
          cf[j] = *reinterpret_cast<const float4*>(&cbS[tx + 16 * j][c4 * 4]);
#pragma unroll
        for (int r = 0; r < 8; ++r) {
          float4 zf = *reinterpret_cast<const float4*>(&zeS[ty + 16 * r][c4 * 4]);
#pragma unroll
          for (int j = 0; j < 8; ++j) {
            acc[r][j] = fmaf(zf.x, cf[j].x, acc[r][j]);
            acc[r][j] = fmaf(zf.y, cf[j].y, acc[r][j]);
            acc[r][j] = fmaf(zf.z, cf[j].z, acc[r][j]);
            acc[r][j] = fmaf(zf.w, cf[j].w, acc[r][j]);
          }
        }
      }
    }

    // top-2 update (scan order ascending in code index per thread).
#pragma unroll
    for (int j = 0; j < 8; ++j) {
      int idx = kc * BKT + tx + 16 * j;
      float cs = cbsq[idx];                  // L2-resident, broadcast-ish
#pragma unroll
      for (int r = 0; r < 8; ++r) {
        float k = fmaf(-2.f, acc[r][j], cs);
        if (k < b2k[r]) {
          if (k < b1k[r]) { b2k[r] = b1k[r]; b2i[r] = b1i[r]; b1k[r] = k; b1i[r] = idx; }
          else            { b2k[r] = k; b2i[r] = idx; }
        }
      }
    }
  }

  // Per-row top-4 of 16 threads x top-2 = 32 distinct candidates (alias smem).
  __syncthreads();
  float (*sKey)[32] = reinterpret_cast<float(*)[32]>(smem);                 // 16384 B
  int (*sIdx)[32] = reinterpret_cast<int(*)[32]>(smem + BN * 32);           // 16384 B
#pragma unroll
  for (int r = 0; r < 8; ++r) {
    int row = ty + 16 * r;
    sKey[row][tx * 2] = b1k[r];     sIdx[row][tx * 2] = b1i[r];
    sKey[row][tx * 2 + 1] = b2k[r]; sIdx[row][tx * 2 + 1] = b2i[r];
  }
  __syncthreads();
  if (tid < BN) {
    int row = tid;
    float k0 = 3e38f, k1 = 3e38f, k2 = 3e38f, k3 = 3e38f;
    int i0 = 0, i1 = 0, i2 = 0, i3 = 0;
    for (int t = 0; t < 32; ++t) {
      float v = sKey[row][t];
      int ii = sIdx[row][t];
      if (v < k3) {
        if (v < k2) {
          k3 = k2; i3 = i2;
          if (v < k1) {
            k2 = k1; i2 = i1;
            if (v < k0) { k1 = k0; i1 = i0; k0 = v; i0 = ii; }
            else        { k1 = v; i1 = ii; }
          } else { k2 = v; i2 = ii; }
        } else { k3 = v; i3 = ii; }
      }
    }
    ushort4 c;
    c.x = (ushort)i0; c.y = (ushort)i1; c.z = (ushort)i2; c.w = (ushort)i3;
    reinterpret_cast<ushort4*>(cand)[rowbase + row] = c;
  }
}

// ---------------------------------------------------------------------------
// Kernel 3: exact-fp32-replication rescore (FROZEN semantics from R3-pass):
//   key = fl32( fl32( zs - fl32(2*cross_fp64) ) + cb_sq32 ), tie -> low idx.
// zs fused in (same shfl_xor fp64 tree as the R3 sqnorm -> bit-identical).
// Winner: gather z_q + fp64 loss partial; no global atomics.
// ---------------------------------------------------------------------------
__global__ __launch_bounds__(256) void rescore_kernel(
    const float* __restrict__ ze, const float* __restrict__ cb,
    const float* __restrict__ cbsq, const ushort* __restrict__ cand,
    float* __restrict__ zq, float* __restrict__ idx_f,
    double* __restrict__ partial) {
  int w = threadIdx.x >> 6, lane = threadIdx.x & 63;
  int row = blockIdx.x * NROW_B + w;
  ushort4 c4 = reinterpret_cast<const ushort4*>(cand)[row];
  int ci[4] = {c4.x, c4.y, c4.z, c4.w};
  float2 z = reinterpret_cast<const float2*>(ze)[(size_t)row * 64 + lane];

  double zsum = (double)z.x * (double)z.x + (double)z.y * (double)z.y;
#pragma unroll
  for (int off = 32; off >= 1; off >>= 1) zsum += __shfl_xor(zsum, off, 64);
  float zs = (float)zsum;

  float best = 3.4e38f;
  int bidx = K_CB + 1;
  float2 bc = make_float2(0.f, 0.f);
#pragma unroll
  for (int j = 0; j < 4; ++j) {
    float2 c = reinterpret_cast<const float2*>(cb)[(size_t)ci[j] * 64 + lane];
    double p = (double)z.x * (double)c.x + (double)z.y * (double)c.y;
#pragma unroll
    for (int off = 32; off >= 1; off >>= 1) p += __shfl_xor(p, off, 64);
    float t = (float)(2.0 * p);       // fl32(2*cross)
    float u = zs - t;                 // fl32(ze_sq - t)
    float d = u + cbsq[ci[j]];        // fl32(u + cb_sq)
    if (d < best || (d == best && ci[j] < bidx)) { best = d; bidx = ci[j]; bc = c; }
  }

  reinterpret_cast<float2*>(zq)[(size_t)row * 64 + lane] = bc;

  double dx = (double)z.x - (double)bc.x;
  double dy = (double)z.y - (double)bc.y;
  double l = dx * dx + dy * dy;
#pragma unroll
  for (int off = 32; off >= 1; off >>= 1) l += __shfl_xor(l, off, 64);

  __shared__ double sh[NROW_B];
  if (lane == 0) { idx_f[row] = (float)bidx; sh[w] = l; }
  __syncthreads();
  if (threadIdx.x == 0) partial[blockIdx.x] = sh[0] + sh[1] + sh[2] + sh[3];
}

__global__ __launch_bounds__(256) void finalize_kernel(
    const double* __restrict__ partial, float* __restrict__ out_loss) {
  double s = 0.0;
  for (int i = threadIdx.x; i < NBLK_B; i += 256) s += partial[i];
#pragma unroll
  for (int off = 32; off >= 1; off >>= 1) s += __shfl_down(s, off, 64);
  __shared__ double sh[4];
  int wv = threadIdx.x >> 6, lane = threadIdx.x & 63;
  if (lane == 0) sh[wv] = s;
  __syncthreads();
  if (threadIdx.x == 0) {
    double tot = sh[0] + sh[1] + sh[2] + sh[3];
    double mse = tot / (double)((size_t)N_TOT * C_DIM);
    *out_loss = (float)(1.75 * mse);  // 0.75*q_latent + e_latent, both == mse
  }
}

// ---------------------------------------------------------------------------
extern "C" void kernel_launch(void* const* d_in, const int* in_sizes, int n_in,
                              void* d_out, int out_size, void* d_ws, size_t ws_size,
                              hipStream_t stream) {
  const float* ze = (const float*)d_in[0];
  const float* cb = (const float*)d_in[1];

  float* out = (float*)d_out;
  float* zq = out;                                   // [N*C]
  float* out_loss = out + (size_t)N_TOT * C_DIM;     // [1]
  float* idx_f = out_loss + 1;                       // [N]

  float* cbsq = (float*)d_ws;                             // 4 KB
  ushort* cand = (ushort*)((char*)d_ws + 266240);         // 512 KB
  double* partial = (double*)((char*)d_ws + 790528);      // 128 KB

  cbsq_kernel<<<K_CB / 4, 256, 0, stream>>>(cb, cbsq);
  dist_topk_kernel<<<N_TOT / BN, 256, 0, stream>>>(ze, cb, cbsq, cand);
  rescore_kernel<<<NBLK_B, 256, 0, stream>>>(ze, cb, cbsq, cand, zq, idx_f, partial);
  finalize_kernel<<<1, 256, 0, stream>>>(partial, out_loss);
}

// Round 6
// 269.276 us; speedup vs baseline: 1.7486x; 1.7486x over previous
//
#include <hip/hip_runtime.h>

#define N_TOT 65536
#define C_DIM 128
#define K_CB  1024
#define BN 64          // z rows per filter block
#define BT 64          // codes per tile
#define NTILE (K_CB / BT)
#define LDB 136        // LDS row stride in bf16 elems (272 B, 16B-aligned)
#define NROW_B 4
#define NBLK_B (N_TOT / NROW_B)

typedef __attribute__((ext_vector_type(8))) short bf16x8;   // 8 bf16 = 4 VGPR
typedef __attribute__((ext_vector_type(4))) float f32x4;

__device__ __forceinline__ ushort f2bf_rne(float f) {
  unsigned u = __float_as_uint(f);
  unsigned r = (u + 0x7FFFu + ((u >> 16) & 1u)) >> 16;
  return (ushort)r;
}
__device__ __forceinline__ float bf2f(ushort h) {
  return __uint_as_float(((unsigned)h) << 16);
}

// ---------------------------------------------------------------------------
// cb_sq[k] = fl32( fp64 sum c^2 ) — one wave per code row. (frozen)
// ---------------------------------------------------------------------------
__global__ __launch_bounds__(256) void cbsq_kernel(const float* __restrict__ cb,
                                                   float* __restrict__ out) {
  int w = threadIdx.x >> 6, lane = threadIdx.x & 63;
  int r = blockIdx.x * 4 + w;
  float2 v = reinterpret_cast<const float2*>(cb + (size_t)r * C_DIM)[lane];
  double s = (double)v.x * (double)v.x + (double)v.y * (double)v.y;
#pragma unroll
  for (int off = 32; off >= 1; off >>= 1) s += __shfl_xor(s, off, 64);
  if (lane == 0) out[r] = (float)s;
}

// ---------------------------------------------------------------------------
// Split codebook into bf16 hi/lo planes (RNE). 32768 float4 chunks total.
// ---------------------------------------------------------------------------
__global__ __launch_bounds__(256) void cbconv_kernel(const float* __restrict__ cb,
                                                     ushort* __restrict__ cbh,
                                                     ushort* __restrict__ cbl) {
  int gid = blockIdx.x * 256 + threadIdx.x;   // 0..32767
  float4 v = reinterpret_cast<const float4*>(cb)[gid];
  ushort4 h, l;
  h.x = f2bf_rne(v.x); l.x = f2bf_rne(v.x - bf2f(h.x));
  h.y = f2bf_rne(v.y); l.y = f2bf_rne(v.y - bf2f(h.y));
  h.z = f2bf_rne(v.z); l.z = f2bf_rne(v.z - bf2f(h.z));
  h.w = f2bf_rne(v.w); l.w = f2bf_rne(v.w - bf2f(h.w));
  reinterpret_cast<ushort4*>(cbh)[gid] = h;
  reinterpret_cast<ushort4*>(cbl)[gid] = l;
}

// ---------------------------------------------------------------------------
// MFMA filter: per-row TOP-4 candidates via 3-pass bf16-split distances.
// Block: 256 thr = 4 waves in 2x2 (m-half x n-half); 64 rows x 64-code tiles.
// Wave tile 32x32 per code-tile using mfma_f32_16x16x32_bf16 (2x2 subtiles).
// key = cbsq[k] - 2*dot; noise sigma ~4e-6 << top-4 margin -> np pick safe.
// ---------------------------------------------------------------------------
__global__ __launch_bounds__(256, 2) void dist_mfma_kernel(
    const float* __restrict__ ze, const ushort* __restrict__ cbh,
    const ushort* __restrict__ cbl, const float* __restrict__ cbsq,
    ushort* __restrict__ cand) {
  __shared__ ushort zh[BN][LDB], zl[BN][LDB];   // 2 x 17408 B
  __shared__ ushort ch[BT][LDB], cl[BT][LDB];   // 2 x 17408 B (aliased at end)

  const int tid = threadIdx.x;
  const int w = tid >> 6, lane = tid & 63;
  const int mh = w & 1, nh = w >> 1;            // wave quadrant
  const int c16 = lane & 15, quad = lane >> 4;
  const int rowbase = blockIdx.x * BN;

  // Stage z tile once: 64 rows x 32 float4, split to bf16 hi/lo in LDS.
#pragma unroll
  for (int i = 0; i < 8; ++i) {
    int fid = i * 256 + tid;
    int row = fid >> 5, c4 = fid & 31;
    float4 v = reinterpret_cast<const float4*>(ze)[(size_t)(rowbase + row) * 32 + c4];
    ushort4 h, l;
    h.x = f2bf_rne(v.x); l.x = f2bf_rne(v.x - bf2f(h.x));
    h.y = f2bf_rne(v.y); l.y = f2bf_rne(v.y - bf2f(h.y));
    h.z = f2bf_rne(v.z); l.z = f2bf_rne(v.z - bf2f(h.z));
    h.w = f2bf_rne(v.w); l.w = f2bf_rne(v.w - bf2f(h.w));
    *reinterpret_cast<ushort4*>(&zh[row][c4 * 4]) = h;
    *reinterpret_cast<ushort4*>(&zl[row][c4 * 4]) = l;
  }

  // top-2 state per slot s = m2*4+reg (8 row-slots per lane).
  float b1k[8], b2k[8];
  int b1i[8], b2i[8];
#pragma unroll
  for (int s = 0; s < 8; ++s) { b1k[s] = 3e38f; b2k[s] = 3e38f; b1i[s] = 0; b2i[s] = 0; }

  for (int t = 0; t < NTILE; ++t) {
    __syncthreads();   // prev tile consumed (and t=0: z staging visible after 2nd)
    // Stage cb tile: 64 codes x 16 uint4-chunks per plane.
#pragma unroll
    for (int i = 0; i < 4; ++i) {
      int fid = i * 256 + tid;
      int row = fid >> 4, c8 = fid & 15;
      *reinterpret_cast<uint4*>(&ch[row][c8 * 8]) =
          reinterpret_cast<const uint4*>(cbh)[(size_t)(t * BT + row) * 16 + c8];
      *reinterpret_cast<uint4*>(&cl[row][c8 * 8]) =
          reinterpret_cast<const uint4*>(cbl)[(size_t)(t * BT + row) * 16 + c8];
    }
    __syncthreads();

    f32x4 acc[2][2];
#pragma unroll
    for (int m2 = 0; m2 < 2; ++m2)
#pragma unroll
      for (int n2 = 0; n2 < 2; ++n2) acc[m2][n2] = (f32x4){0.f, 0.f, 0.f, 0.f};

#pragma unroll 2
    for (int ks = 0; ks < 4; ++ks) {
      const int off = ks * 32 + quad * 8;
      bf16x8 ah[2], al[2], bh[2], bl[2];
#pragma unroll
      for (int m2 = 0; m2 < 2; ++m2) {
        int r = mh * 32 + m2 * 16 + c16;
        ah[m2] = *reinterpret_cast<const bf16x8*>(&zh[r][off]);
        al[m2] = *reinterpret_cast<const bf16x8*>(&zl[r][off]);
      }
#pragma unroll
      for (int n2 = 0; n2 < 2; ++n2) {
        int cr = nh * 32 + n2 * 16 + c16;
        bh[n2] = *reinterpret_cast<const bf16x8*>(&ch[cr][off]);
        bl[n2] = *reinterpret_cast<const bf16x8*>(&cl[cr][off]);
      }
#pragma unroll
      for (int m2 = 0; m2 < 2; ++m2)
#pragma unroll
        for (int n2 = 0; n2 < 2; ++n2) {
          acc[m2][n2] = __builtin_amdgcn_mfma_f32_16x16x32_bf16(ah[m2], bh[n2], acc[m2][n2], 0, 0, 0);
          acc[m2][n2] = __builtin_amdgcn_mfma_f32_16x16x32_bf16(ah[m2], bl[n2], acc[m2][n2], 0, 0, 0);
          acc[m2][n2] = __builtin_amdgcn_mfma_f32_16x16x32_bf16(al[m2], bh[n2], acc[m2][n2], 0, 0, 0);
        }
    }

    // keys + top-2 update. D layout: col=lane&15, row=quad*4+reg (m89-verified).
#pragma unroll
    for (int n2 = 0; n2 < 2; ++n2) {
      int code = t * BT + nh * 32 + n2 * 16 + c16;
      float cs = cbsq[code];
#pragma unroll
      for (int m2 = 0; m2 < 2; ++m2)
#pragma unroll
        for (int reg = 0; reg < 4; ++reg) {
          float k = fmaf(-2.f, acc[m2][n2][reg], cs);
          int s = m2 * 4 + reg;
          if (k < b2k[s]) {
            if (k < b1k[s]) { b2k[s] = b1k[s]; b2i[s] = b1i[s]; b1k[s] = k; b1i[s] = code; }
            else            { b2k[s] = k; b2i[s] = code; }
          }
        }
    }
  }

  // Per-row top-4 of 64 candidates (2 n-half waves x 16 lanes x top-2).
  __syncthreads();
  float* keyF = reinterpret_cast<float*>(&ch[0][0]);   // [64][65] = 16640 B
  int* idxI = reinterpret_cast<int*>(&cl[0][0]);       // [64][65] = 16640 B
#pragma unroll
  for (int s = 0; s < 8; ++s) {
    int m2 = s >> 2, reg = s & 3;
    int row = mh * 32 + m2 * 16 + quad * 4 + reg;
    int col = nh * 32 + c16 * 2;
    keyF[row * 65 + col] = b1k[s];     idxI[row * 65 + col] = b1i[s];
    keyF[row * 65 + col + 1] = b2k[s]; idxI[row * 65 + col + 1] = b2i[s];
  }
  __syncthreads();
  if (tid < BN) {
    int row = tid;
    float k0 = 3e38f, k1 = 3e38f, k2 = 3e38f, k3 = 3e38f;
    int i0 = 0, i1 = 0, i2 = 0, i3 = 0;
    for (int t = 0; t < 64; ++t) {
      float v = keyF[row * 65 + t];
      int ii = idxI[row * 65 + t];
      if (v < k3) {
        if (v < k2) {
          k3 = k2; i3 = i2;
          if (v < k1) {
            k2 = k1; i2 = i1;
            if (v < k0) { k1 = k0; i1 = i0; k0 = v; i0 = ii; }
            else        { k1 = v; i1 = ii; }
          } else { k2 = v; i2 = ii; }
        } else { k3 = v; i3 = ii; }
      }
    }
    ushort4 c;
    c.x = (ushort)i0; c.y = (ushort)i1; c.z = (ushort)i2; c.w = (ushort)i3;
    reinterpret_cast<ushort4*>(cand)[rowbase + row] = c;
  }
}

// ---------------------------------------------------------------------------
// Rescore (FROZEN from R3-pass): replicate numpy fp32 key
//   key = fl32( fl32( zs - fl32(2*cross_fp64) ) + cb_sq32 ), tie -> low idx.
// Winner: gather z_q + fp64 loss partial; no global atomics.
// ---------------------------------------------------------------------------
__global__ __launch_bounds__(256) void rescore_kernel(
    const float* __restrict__ ze, const float* __restrict__ cb,
    const float* __restrict__ cbsq, const ushort* __restrict__ cand,
    float* __restrict__ zq, float* __restrict__ idx_f,
    double* __restrict__ partial) {
  int w = threadIdx.x >> 6, lane = threadIdx.x & 63;
  int row = blockIdx.x * NROW_B + w;
  ushort4 c4 = reinterpret_cast<const ushort4*>(cand)[row];
  int ci[4] = {c4.x, c4.y, c4.z, c4.w};
  float2 z = reinterpret_cast<const float2*>(ze)[(size_t)row * 64 + lane];

  double zsum = (double)z.x * (double)z.x + (double)z.y * (double)z.y;
#pragma unroll
  for (int off = 32; off >= 1; off >>= 1) zsum += __shfl_xor(zsum, off, 64);
  float zs = (float)zsum;

  float best = 3.4e38f;
  int bidx = K_CB + 1;
  float2 bc = make_float2(0.f, 0.f);
#pragma unroll
  for (int j = 0; j < 4; ++j) {
    float2 c = reinterpret_cast<const float2*>(cb)[(size_t)ci[j] * 64 + lane];
    double p = (double)z.x * (double)c.x + (double)z.y * (double)c.y;
#pragma unroll
    for (int off = 32; off >= 1; off >>= 1) p += __shfl_xor(p, off, 64);
    float t = (float)(2.0 * p);       // fl32(2*cross)
    float u = zs - t;                 // fl32(ze_sq - t)
    float d = u + cbsq[ci[j]];        // fl32(u + cb_sq)
    if (d < best || (d == best && ci[j] < bidx)) { best = d; bidx = ci[j]; bc = c; }
  }

  reinterpret_cast<float2*>(zq)[(size_t)row * 64 + lane] = bc;

  double dx = (double)z.x - (double)bc.x;
  double dy = (double)z.y - (double)bc.y;
  double l = dx * dx + dy * dy;
#pragma unroll
  for (int off = 32; off >= 1; off >>= 1) l += __shfl_xor(l, off, 64);

  __shared__ double sh[NROW_B];
  if (lane == 0) { idx_f[row] = (float)bidx; sh[w] = l; }
  __syncthreads();
  if (threadIdx.x == 0) partial[blockIdx.x] = sh[0] + sh[1] + sh[2] + sh[3];
}

__global__ __launch_bounds__(256) void finalize_kernel(
    const double* __restrict__ partial, float* __restrict__ out_loss) {
  double s = 0.0;
  for (int i = threadIdx.x; i < NBLK_B; i += 256) s += partial[i];
#pragma unroll
  for (int off = 32; off >= 1; off >>= 1) s += __shfl_down(s, off, 64);
  __shared__ double sh[4];
  int wv = threadIdx.x >> 6, lane = threadIdx.x & 63;
  if (lane == 0) sh[wv] = s;
  __syncthreads();
  if (threadIdx.x == 0) {
    double tot = sh[0] + sh[1] + sh[2] + sh[3];
    double mse = tot / (double)((size_t)N_TOT * C_DIM);
    *out_loss = (float)(1.75 * mse);  // 0.75*q_latent + e_latent, both == mse
  }
}

// ---------------------------------------------------------------------------
extern "C" void kernel_launch(void* const* d_in, const int* in_sizes, int n_in,
                              void* d_out, int out_size, void* d_ws, size_t ws_size,
                              hipStream_t stream) {
  const float* ze = (const float*)d_in[0];
  const float* cb = (const float*)d_in[1];

  float* out = (float*)d_out;
  float* zq = out;                                   // [N*C]
  float* out_loss = out + (size_t)N_TOT * C_DIM;     // [1]
  float* idx_f = out_loss + 1;                       // [N]

  // ws: cbsq 4KB @0 | cbh 256KB @8192 | cbl 256KB @270336 |
  //     cand 512KB @532480 | partial 128KB @1056768. Total ~1.19 MB.
  float* cbsq = (float*)d_ws;
  ushort* cbh = (ushort*)((char*)d_ws + 8192);
  ushort* cbl = (ushort*)((char*)d_ws + 270336);
  ushort* cand = (ushort*)((char*)d_ws + 532480);
  double* partial = (double*)((char*)d_ws + 1056768);

  cbsq_kernel<<<K_CB / 4, 256, 0, stream>>>(cb, cbsq);
  cbconv_kernel<<<K_CB * C_DIM / 4 / 256, 256, 0, stream>>>(cb, cbh, cbl);
  dist_mfma_kernel<<<N_TOT / BN, 256, 0, stream>>>(ze, cbh, cbl, cbsq, cand);
  rescore_kernel<<<NBLK_B, 256, 0, stream>>>(ze, cb, cbsq, cand, zq, idx_f, partial);
  finalize_kernel<<<1, 256, 0, stream>>>(partial, out_loss);
}

// Round 7
// 241.492 us; speedup vs baseline: 1.9498x; 1.1151x over previous
//
#include <hip/hip_runtime.h>

#define N_TOT 65536
#define C_DIM 128
#define K_CB  1024
#define BN 64          // z rows per filter block
#define BT 64          // codes per tile
#define NTILE (K_CB / BT)
#define NROW_B 4
#define NBLK_B (N_TOT / NROW_B)

typedef __attribute__((ext_vector_type(8))) short bf16x8;   // 8 bf16 = 4 VGPR
typedef __attribute__((ext_vector_type(4))) float f32x4;

__device__ __forceinline__ ushort f2bf_rne(float f) {
  unsigned u = __float_as_uint(f);
  return (ushort)((u + 0x7FFFu + ((u >> 16) & 1u)) >> 16);
}

// ---------------------------------------------------------------------------
// cb_sq[k] = fl32( fp64 sum c^2 ) — one wave per code row. (frozen)
// ---------------------------------------------------------------------------
__global__ __launch_bounds__(256) void cbsq_kernel(const float* __restrict__ cb,
                                                   float* __restrict__ out) {
  int w = threadIdx.x >> 6, lane = threadIdx.x & 63;
  int r = blockIdx.x * 4 + w;
  float2 v = reinterpret_cast<const float2*>(cb + (size_t)r * C_DIM)[lane];
  double s = (double)v.x * (double)v.x + (double)v.y * (double)v.y;
#pragma unroll
  for (int off = 32; off >= 1; off >>= 1) s += __shfl_xor(s, off, 64);
  if (lane == 0) out[r] = (float)s;
}

// ---------------------------------------------------------------------------
// Codebook -> bf16 hi plane only (single-pass filter: sigma~1.6e-3 << gaps).
// ---------------------------------------------------------------------------
__global__ __launch_bounds__(256) void cbconv_kernel(const float* __restrict__ cb,
                                                     ushort* __restrict__ cbh) {
  int gid = blockIdx.x * 256 + threadIdx.x;   // 0..32767 float4s
  float4 v = reinterpret_cast<const float4*>(cb)[gid];
  ushort4 h;
  h.x = f2bf_rne(v.x); h.y = f2bf_rne(v.y);
  h.z = f2bf_rne(v.z); h.w = f2bf_rne(v.w);
  reinterpret_cast<ushort4*>(cbh)[gid] = h;
}

// ---------------------------------------------------------------------------
// MFMA filter: single bf16 pass; per-lane TOP-3 over its 32-code groups;
// per-row pool 96 -> TOP-8 candidates. XOR-swizzled LDS (16B chunk ^ (row&7)):
// conflict-free ds_read_b128/ds_write_b128 (R6's pad-136 gave 4 cyc/read).
// 4 waves in 2x2 (mh x nh); wave computes 32x32 per tile as 2x2 16x16x32.
// ---------------------------------------------------------------------------
__global__ __launch_bounds__(256, 4) void dist_mfma_kernel(
    const float* __restrict__ ze, const ushort* __restrict__ cbh,
    const float* __restrict__ cbsq, ushort* __restrict__ cand) {
  // main phase: zhS 16 KB + chS 16 KB; tail phase (aliased): keyP+idxP 37 KB
  __shared__ __align__(16) char smem[37376];
  ushort* zhS = reinterpret_cast<ushort*>(smem);            // [64][128]
  ushort* chS = reinterpret_cast<ushort*>(smem + 16384);    // [64][128]
  float* keyP = reinterpret_cast<float*>(smem);             // [64][97]
  ushort* idxP = reinterpret_cast<ushort*>(smem + 24832);   // [64][98]

  const int tid = threadIdx.x;
  const int w = tid >> 6, lane = tid & 63;
  const int mh = w & 1, nh = w >> 1;
  const int c16 = lane & 15, quad = lane >> 4;
  const int rowbase = blockIdx.x * BN;

  // Stage z tile: 64 rows x 16 chunks(16B bf16x8); thread converts 8 floats.
#pragma unroll
  for (int p = 0; p < 4; ++p) {
    int fid = p * 256 + tid;
    int row = fid >> 4, c8 = fid & 15;
    float4 a = reinterpret_cast<const float4*>(ze)[(size_t)(rowbase + row) * 32 + c8 * 2];
    float4 b = reinterpret_cast<const float4*>(ze)[(size_t)(rowbase + row) * 32 + c8 * 2 + 1];
    ushort h[8] = {f2bf_rne(a.x), f2bf_rne(a.y), f2bf_rne(a.z), f2bf_rne(a.w),
                   f2bf_rne(b.x), f2bf_rne(b.y), f2bf_rne(b.z), f2bf_rne(b.w)};
    *reinterpret_cast<uint4*>(&zhS[row * 128 + ((c8 ^ (row & 7)) * 8)]) =
        *reinterpret_cast<const uint4*>(h);
  }

  // per-lane top-3 per row-slot s = m2*4+reg
  float b1k[8], b2k[8], b3k[8];
  int b1i[8], b2i[8], b3i[8];
#pragma unroll
  for (int s = 0; s < 8; ++s) {
    b1k[s] = 3e38f; b2k[s] = 3e38f; b3k[s] = 3e38f;
    b1i[s] = 0; b2i[s] = 0; b3i[s] = 0;
  }

  const int xk = c16 & 7;                 // shared xor key for all frag rows
  const int rA = (mh * 32 + c16) * 128;   // A base (m2=0); m2=1 -> +2048
  const int rB = (nh * 32 + c16) * 128;

  for (int t = 0; t < NTILE; ++t) {
    __syncthreads();   // prev tile consumed (t=0: pairs with staging sync below)
#pragma unroll
    for (int i = 0; i < 4; ++i) {
      int fid = i * 256 + tid;
      int row = fid >> 4, c8 = fid & 15;
      *reinterpret_cast<uint4*>(&chS[row * 128 + ((c8 ^ (row & 7)) * 8)]) =
          reinterpret_cast<const uint4*>(cbh)[(size_t)(t * BT + row) * 16 + c8];
    }
    __syncthreads();

    f32x4 acc[2][2];
#pragma unroll
    for (int m2 = 0; m2 < 2; ++m2)
#pragma unroll
      for (int n2 = 0; n2 < 2; ++n2) acc[m2][n2] = (f32x4){0.f, 0.f, 0.f, 0.f};

#pragma unroll 2
    for (int ks = 0; ks < 4; ++ks) {
      const int off = ((ks * 4 + quad) ^ xk) * 8;
      bf16x8 ah[2], bh[2];
      ah[0] = *reinterpret_cast<const bf16x8*>(&zhS[rA + off]);
      ah[1] = *reinterpret_cast<const bf16x8*>(&zhS[rA + 2048 + off]);
      bh[0] = *reinterpret_cast<const bf16x8*>(&chS[rB + off]);
      bh[1] = *reinterpret_cast<const bf16x8*>(&chS[rB + 2048 + off]);
#pragma unroll
      for (int m2 = 0; m2 < 2; ++m2)
#pragma unroll
        for (int n2 = 0; n2 < 2; ++n2)
          acc[m2][n2] = __builtin_amdgcn_mfma_f32_16x16x32_bf16(ah[m2], bh[n2], acc[m2][n2], 0, 0, 0);
    }

    // keys + top-3 update. D layout: col=lane&15, row=quad*4+reg (m89).
#pragma unroll
    for (int n2 = 0; n2 < 2; ++n2) {
      int code = t * BT + nh * 32 + n2 * 16 + c16;
      float cs = cbsq[code];
#pragma unroll
      for (int m2 = 0; m2 < 2; ++m2)
#pragma unroll
        for (int reg = 0; reg < 4; ++reg) {
          float k = fmaf(-2.f, acc[m2][n2][reg], cs);
          int s = m2 * 4 + reg;
          if (k < b3k[s]) {
            if (k < b2k[s]) {
              b3k[s] = b2k[s]; b3i[s] = b2i[s];
              if (k < b1k[s]) { b2k[s] = b1k[s]; b2i[s] = b1i[s]; b1k[s] = k; b1i[s] = code; }
              else            { b2k[s] = k; b2i[s] = code; }
            } else { b3k[s] = k; b3i[s] = code; }
          }
        }
    }
  }

  // Pool write: 32 lane-groups x top-3 = 96 per row (strides 97/98: 2-way max).
  __syncthreads();
#pragma unroll
  for (int s = 0; s < 8; ++s) {
    int row = mh * 32 + (s >> 2) * 16 + quad * 4 + (s & 3);
    int col = (nh * 16 + c16) * 3;
    keyP[row * 97 + col] = b1k[s];     idxP[row * 98 + col] = (ushort)b1i[s];
    keyP[row * 97 + col + 1] = b2k[s]; idxP[row * 98 + col + 1] = (ushort)b2i[s];
    keyP[row * 97 + col + 2] = b3k[s]; idxP[row * 98 + col + 2] = (ushort)b3i[s];
  }
  __syncthreads();
  if (tid < BN) {
    int row = tid;
    float k[8];
    int id[8];
#pragma unroll
    for (int q = 0; q < 8; ++q) { k[q] = 3e38f; id[q] = 0; }
    for (int p = 0; p < 96; ++p) {
      float v = keyP[row * 97 + p];
      int ii = idxP[row * 98 + p];
      if (v < k[7]) {
        k[7] = v; id[7] = ii;
#pragma unroll
        for (int q = 7; q > 0; --q)
          if (k[q] < k[q - 1]) {
            float tk = k[q]; k[q] = k[q - 1]; k[q - 1] = tk;
            int ti = id[q]; id[q] = id[q - 1]; id[q - 1] = ti;
          }
      }
    }
    uint4 cw;
    cw.x = (unsigned)id[0] | ((unsigned)id[1] << 16);
    cw.y = (unsigned)id[2] | ((unsigned)id[3] << 16);
    cw.z = (unsigned)id[4] | ((unsigned)id[5] << 16);
    cw.w = (unsigned)id[6] | ((unsigned)id[7] << 16);
    reinterpret_cast<uint4*>(cand)[rowbase + row] = cw;
  }
}

// ---------------------------------------------------------------------------
// Rescore (R3-verified semantics): np fp32 key
//   key = fl32( fl32( zs - fl32(2*cross_fp64) ) + cb_sq32 ), tie -> low idx.
// Lane-split: 8 lanes per candidate (16 dims each), 3-level fp64 tree.
// fp64 regrouping leaves the fp32-rounded key unchanged (~1e-14 rel).
// zs keeps R3's exact 6-level float2 tree. One wave per row.
// ---------------------------------------------------------------------------
__global__ __launch_bounds__(256) void rescore_kernel(
    const float* __restrict__ ze, const float* __restrict__ cb,
    const float* __restrict__ cbsq, const ushort* __restrict__ cand,
    float* __restrict__ zq, float* __restrict__ idx_f,
    double* __restrict__ partial) {
  int w = threadIdx.x >> 6, lane = threadIdx.x & 63;
  int row = blockIdx.x * NROW_B + w;
  int g = lane >> 3, e = lane & 7;      // candidate group, 16-dim segment
  int myc = cand[(size_t)row * 8 + g];

  float2 z2 = reinterpret_cast<const float2*>(ze)[(size_t)row * 64 + lane];
  double zsum = (double)z2.x * (double)z2.x + (double)z2.y * (double)z2.y;
#pragma unroll
  for (int off = 32; off >= 1; off >>= 1) zsum += __shfl_xor(zsum, off, 64);
  float zs = (float)zsum;

  const float4* zrow4 = reinterpret_cast<const float4*>(ze + (size_t)row * C_DIM);
  const float4* crow4 = reinterpret_cast<const float4*>(cb + (size_t)myc * C_DIM);
  double p = 0.0;
#pragma unroll
  for (int q = 0; q < 4; ++q) {
    float4 zz = zrow4[e * 4 + q];
    float4 cc = crow4[e * 4 + q];
    p += (double)zz.x * (double)cc.x + (double)zz.y * (double)cc.y +
         (double)zz.z * (double)cc.z + (double)zz.w * (double)cc.w;
  }
  p += __shfl_xor(p, 1, 64);
  p += __shfl_xor(p, 2, 64);
  p += __shfl_xor(p, 4, 64);            // all 8 lanes of group hold the dot

  float tt = (float)(2.0 * p);          // fl32(2*cross)
  float u = zs - tt;                    // fl32(ze_sq - t)
  float d = u + cbsq[myc];              // fl32(u + cb_sq)

  float best = 3.4e38f;
  int bidx = K_CB + 1;
#pragma unroll
  for (int gg = 0; gg < 8; ++gg) {
    float dg = __shfl(d, gg * 8, 64);
    int ig = __shfl(myc, gg * 8, 64);
    if (dg < best || (dg == best && ig < bidx)) { best = dg; bidx = ig; }
  }

  float2 c2 = reinterpret_cast<const float2*>(cb)[(size_t)bidx * 64 + lane];
  reinterpret_cast<float2*>(zq)[(size_t)row * 64 + lane] = c2;

  double dx = (double)z2.x - (double)c2.x;
  double dy = (double)z2.y - (double)c2.y;
  double l = dx * dx + dy * dy;
#pragma unroll
  for (int off = 32; off >= 1; off >>= 1) l += __shfl_xor(l, off, 64);

  __shared__ double sh[NROW_B];
  if (lane == 0) { idx_f[row] = (float)bidx; sh[w] = l; }
  __syncthreads();
  if (threadIdx.x == 0) partial[blockIdx.x] = sh[0] + sh[1] + sh[2] + sh[3];
}

__global__ __launch_bounds__(256) void finalize_kernel(
    const double* __restrict__ partial, float* __restrict__ out_loss) {
  double s = 0.0;
  for (int i = threadIdx.x; i < NBLK_B; i += 256) s += partial[i];
#pragma unroll
  for (int off = 32; off >= 1; off >>= 1) s += __shfl_down(s, off, 64);
  __shared__ double sh[4];
  int wv = threadIdx.x >> 6, lane = threadIdx.x & 63;
  if (lane == 0) sh[wv] = s;
  __syncthreads();
  if (threadIdx.x == 0) {
    double tot = sh[0] + sh[1] + sh[2] + sh[3];
    double mse = tot / (double)((size_t)N_TOT * C_DIM);
    *out_loss = (float)(1.75 * mse);  // 0.75*q_latent + e_latent, both == mse
  }
}

// ---------------------------------------------------------------------------
extern "C" void kernel_launch(void* const* d_in, const int* in_sizes, int n_in,
                              void* d_out, int out_size, void* d_ws, size_t ws_size,
                              hipStream_t stream) {
  const float* ze = (const float*)d_in[0];
  const float* cb = (const float*)d_in[1];

  float* out = (float*)d_out;
  float* zq = out;                                   // [N*C]
  float* out_loss = out + (size_t)N_TOT * C_DIM;     // [1]
  float* idx_f = out_loss + 1;                       // [N]

  // ws: cbsq 4KB @0 | cbh 256KB @8192 | cand(ushort8) 1MB @270336 |
  //     partial 128KB @1318912. Total ~1.38 MB.
  float* cbsq = (float*)d_ws;
  ushort* cbh = (ushort*)((char*)d_ws + 8192);
  ushort* cand = (ushort*)((char*)d_ws + 270336);
  double* partial = (double*)((char*)d_ws + 1318912);

  cbsq_kernel<<<K_CB / 4, 256, 0, stream>>>(cb, cbsq);
  cbconv_kernel<<<K_CB * C_DIM / 4 / 256, 256, 0, stream>>>(cb, cbh);
  dist_mfma_kernel<<<N_TOT / BN, 256, 0, stream>>>(ze, cbh, cbsq, cand);
  rescore_kernel<<<NBLK_B, 256, 0, stream>>>(ze, cb, cbsq, cand, zq, idx_f, partial);
  finalize_kernel<<<1, 256, 0, stream>>>(partial, out_loss);
}

// Round 8
// 209.777 us; speedup vs baseline: 2.2446x; 1.1512x over previous
//
#include <hip/hip_runtime.h>

#define N_TOT 65536
#define C_DIM 128
#define K_CB  1024
#define BN 64
#define BT 64
#define NTILE (K_CB / BT)
#define NROW_B 4
#define NBLK_B (N_TOT / NROW_B)

typedef __attribute__((ext_vector_type(8))) short bf16x8;   // 8 bf16 = 4 VGPR
typedef __attribute__((ext_vector_type(4))) float f32x4;

__device__ __forceinline__ ushort f2bf_rne(float f) {
  unsigned u = __float_as_uint(f);
  return (ushort)((u + 0x7FFFu + ((u >> 16) & 1u)) >> 16);
}

// ---------------------------------------------------------------------------
// cb_sq[k] = fl32( fp64 sum c^2 ) — one wave per code row. (frozen)
// ---------------------------------------------------------------------------
__global__ __launch_bounds__(256) void cbsq_kernel(const float* __restrict__ cb,
                                                   float* __restrict__ out) {
  int w = threadIdx.x >> 6, lane = threadIdx.x & 63;
  int r = blockIdx.x * 4 + w;
  float2 v = reinterpret_cast<const float2*>(cb + (size_t)r * C_DIM)[lane];
  double s = (double)v.x * (double)v.x + (double)v.y * (double)v.y;
#pragma unroll
  for (int off = 32; off >= 1; off >>= 1) s += __shfl_xor(s, off, 64);
  if (lane == 0) out[r] = (float)s;
}

// ---------------------------------------------------------------------------
// Codebook -> bf16 plane (RNE). (frozen)
// ---------------------------------------------------------------------------
__global__ __launch_bounds__(256) void cbconv_kernel(const float* __restrict__ cb,
                                                     ushort* __restrict__ cbh) {
  int gid = blockIdx.x * 256 + threadIdx.x;   // 0..32767 float4s
  float4 v = reinterpret_cast<const float4*>(cb)[gid];
  ushort4 h;
  h.x = f2bf_rne(v.x); h.y = f2bf_rne(v.y);
  h.z = f2bf_rne(v.z); h.w = f2bf_rne(v.w);
  reinterpret_cast<ushort4*>(cbh)[gid] = h;
}

// ---------------------------------------------------------------------------
// MFMA filter, barrier-free K-loop:
//  - A-frags (z) hoisted to regs once (8 x bf16x8); zhS LDS dead after.
//  - B-frags read per tile directly from global cbh (L1/L2-resident 256 KB).
//  - key' = (cbsq[k]+192) - 2*dot  in [183,201] -> positive-float bits are
//    uint-monotone; packed = (bits & ~1023) | code -> top-3 via v_min/max_u32,
//    no index registers. Truncation 0.0156 << per-row gaps; top-8 rescued.
//  - pool stride 97 words (96 = 0 mod 32 banks would 64-way-conflict scans).
// ---------------------------------------------------------------------------
__global__ __launch_bounds__(256, 3) void dist_mfma_kernel(
    const float* __restrict__ ze, const ushort* __restrict__ cbh,
    const float* __restrict__ cbsq, ushort* __restrict__ cand) {
  __shared__ __align__(16) char smem[24832];              // max(z 16384, pool 24832)
  ushort* zhS = reinterpret_cast<ushort*>(smem);          // [64][128] xor-swizzled
  unsigned* pool = reinterpret_cast<unsigned*>(smem);     // [64][97]

  const int tid = threadIdx.x;
  const int w = tid >> 6, lane = tid & 63;
  const int mh = w & 1, nh = w >> 1;
  const int c16 = lane & 15, quad = lane >> 4;
  const int rowbase = blockIdx.x * BN;

  // Stage z tile -> bf16 LDS (one time).
#pragma unroll
  for (int p = 0; p < 4; ++p) {
    int fid = p * 256 + tid;
    int row = fid >> 4, c8 = fid & 15;
    float4 a = reinterpret_cast<const float4*>(ze)[(size_t)(rowbase + row) * 32 + c8 * 2];
    float4 b = reinterpret_cast<const float4*>(ze)[(size_t)(rowbase + row) * 32 + c8 * 2 + 1];
    ushort h[8] = {f2bf_rne(a.x), f2bf_rne(a.y), f2bf_rne(a.z), f2bf_rne(a.w),
                   f2bf_rne(b.x), f2bf_rne(b.y), f2bf_rne(b.z), f2bf_rne(b.w)};
    *reinterpret_cast<uint4*>(&zhS[row * 128 + ((c8 ^ (row & 7)) * 8)]) =
        *reinterpret_cast<const uint4*>(h);
  }
  __syncthreads();

  // Hoist A-frags: afrag[m2][ks], row = mh*32+m2*16+c16, k = ks*32+quad*8.
  const int xk = c16 & 7;
  bf16x8 afrag[2][4];
#pragma unroll
  for (int m2 = 0; m2 < 2; ++m2) {
    int r = (mh * 32 + m2 * 16 + c16) * 128;
#pragma unroll
    for (int ks = 0; ks < 4; ++ks)
      afrag[m2][ks] = *reinterpret_cast<const bf16x8*>(&zhS[r + ((ks * 4 + quad) ^ xk) * 8]);
  }
  __syncthreads();   // zhS dead; pool aliasing safe

  unsigned t3[8][3];
#pragma unroll
  for (int s = 0; s < 8; ++s) { t3[s][0] = 0xFFFFFFFFu; t3[s][1] = 0xFFFFFFFFu; t3[s][2] = 0xFFFFFFFFu; }

  // Per-lane B base: row (nh*32 + c16), elem quad*8.
  const ushort* bbase = cbh + (size_t)(nh * 32 + c16) * 128 + quad * 8;

  for (int t = 0; t < NTILE; ++t) {
    bf16x8 bf[2][4];
#pragma unroll
    for (int n2 = 0; n2 < 2; ++n2)
#pragma unroll
      for (int ks = 0; ks < 4; ++ks)
        bf[n2][ks] = *reinterpret_cast<const bf16x8*>(bbase + t * 8192 + n2 * 2048 + ks * 32);

    f32x4 acc[2][2];
#pragma unroll
    for (int m2 = 0; m2 < 2; ++m2)
#pragma unroll
      for (int n2 = 0; n2 < 2; ++n2) acc[m2][n2] = (f32x4){0.f, 0.f, 0.f, 0.f};

#pragma unroll
    for (int ks = 0; ks < 4; ++ks)
#pragma unroll
      for (int m2 = 0; m2 < 2; ++m2)
#pragma unroll
        for (int n2 = 0; n2 < 2; ++n2)
          acc[m2][n2] = __builtin_amdgcn_mfma_f32_16x16x32_bf16(afrag[m2][ks], bf[n2][ks], acc[m2][n2], 0, 0, 0);

    // keys + packed top-3. D layout: col=lane&15, row=quad*4+reg (m89).
#pragma unroll
    for (int n2 = 0; n2 < 2; ++n2) {
      int code = t * BT + nh * 32 + n2 * 16 + c16;
      float csb = cbsq[code] + 192.0f;
#pragma unroll
      for (int m2 = 0; m2 < 2; ++m2)
#pragma unroll
        for (int reg = 0; reg < 4; ++reg) {
          float kf = fmaf(-2.f, acc[m2][n2][reg], csb);
          unsigned pk = (__float_as_uint(kf) & 0xFFFFFC00u) | (unsigned)code;
          int s = m2 * 4 + reg;
          unsigned c1 = min(t3[s][0], pk), h1 = max(t3[s][0], pk);
          unsigned c2 = min(t3[s][1], h1), h2 = max(t3[s][1], h1);
          unsigned c3 = min(t3[s][2], h2);
          t3[s][0] = c1; t3[s][1] = c2; t3[s][2] = c3;
        }
    }
  }

  // Pool: 32 (nh,c16) groups x top-3 = 96 packed keys per row.
#pragma unroll
  for (int s = 0; s < 8; ++s) {
    int row = mh * 32 + (s >> 2) * 16 + quad * 4 + (s & 3);
    int col = (nh * 16 + c16) * 3;
    pool[row * 97 + col] = t3[s][0];
    pool[row * 97 + col + 1] = t3[s][1];
    pool[row * 97 + col + 2] = t3[s][2];
  }
  __syncthreads();
  if (tid < BN) {
    unsigned k[8];
#pragma unroll
    for (int q = 0; q < 8; ++q) k[q] = 0xFFFFFFFFu;
    for (int p = 0; p < 96; ++p) {
      unsigned v = pool[tid * 97 + p];
      if (v < k[7]) {
        k[7] = v;
#pragma unroll
        for (int q = 7; q > 0; --q)
          if (k[q] < k[q - 1]) { unsigned tk = k[q]; k[q] = k[q - 1]; k[q - 1] = tk; }
      }
    }
    uint4 cw;
    cw.x = (k[0] & 1023u) | ((k[1] & 1023u) << 16);
    cw.y = (k[2] & 1023u) | ((k[3] & 1023u) << 16);
    cw.z = (k[4] & 1023u) | ((k[5] & 1023u) << 16);
    cw.w = (k[6] & 1023u) | ((k[7] & 1023u) << 16);
    reinterpret_cast<uint4*>(cand)[rowbase + tid] = cw;
  }
}

// ---------------------------------------------------------------------------
// Rescore (R3/R7-verified, UNTOUCHED): np fp32 key replication
//   key = fl32( fl32( zs - fl32(2*cross_fp64) ) + cb_sq32 ), tie -> low idx.
// ---------------------------------------------------------------------------
__global__ __launch_bounds__(256) void rescore_kernel(
    const float* __restrict__ ze, const float* __restrict__ cb,
    const float* __restrict__ cbsq, const ushort* __restrict__ cand,
    float* __restrict__ zq, float* __restrict__ idx_f,
    double* __restrict__ partial) {
  int w = threadIdx.x >> 6, lane = threadIdx.x & 63;
  int row = blockIdx.x * NROW_B + w;
  int g = lane >> 3, e = lane & 7;
  int myc = cand[(size_t)row * 8 + g];

  float2 z2 = reinterpret_cast<const float2*>(ze)[(size_t)row * 64 + lane];
  double zsum = (double)z2.x * (double)z2.x + (double)z2.y * (double)z2.y;
#pragma unroll
  for (int off = 32; off >= 1; off >>= 1) zsum += __shfl_xor(zsum, off, 64);
  float zs = (float)zsum;

  const float4* zrow4 = reinterpret_cast<const float4*>(ze + (size_t)row * C_DIM);
  const float4* crow4 = reinterpret_cast<const float4*>(cb + (size_t)myc * C_DIM);
  double p = 0.0;
#pragma unroll
  for (int q = 0; q < 4; ++q) {
    float4 zz = zrow4[e * 4 + q];
    float4 cc = crow4[e * 4 + q];
    p += (double)zz.x * (double)cc.x + (double)zz.y * (double)cc.y +
         (double)zz.z * (double)cc.z + (double)zz.w * (double)cc.w;
  }
  p += __shfl_xor(p, 1, 64);
  p += __shfl_xor(p, 2, 64);
  p += __shfl_xor(p, 4, 64);

  float tt = (float)(2.0 * p);
  float u = zs - tt;
  float d = u + cbsq[myc];

  float best = 3.4e38f;
  int bidx = K_CB + 1;
#pragma unroll
  for (int gg = 0; gg < 8; ++gg) {
    float dg = __shfl(d, gg * 8, 64);
    int ig = __shfl(myc, gg * 8, 64);
    if (dg < best || (dg == best && ig < bidx)) { best = dg; bidx = ig; }
  }

  float2 c2 = reinterpret_cast<const float2*>(cb)[(size_t)bidx * 64 + lane];
  reinterpret_cast<float2*>(zq)[(size_t)row * 64 + lane] = c2;

  double dx = (double)z2.x - (double)c2.x;
  double dy = (double)z2.y - (double)c2.y;
  double l = dx * dx + dy * dy;
#pragma unroll
  for (int off = 32; off >= 1; off >>= 1) l += __shfl_xor(l, off, 64);

  __shared__ double sh[NROW_B];
  if (lane == 0) { idx_f[row] = (float)bidx; sh[w] = l; }
  __syncthreads();
  if (threadIdx.x == 0) partial[blockIdx.x] = sh[0] + sh[1] + sh[2] + sh[3];
}

__global__ __launch_bounds__(256) void finalize_kernel(
    const double* __restrict__ partial, float* __restrict__ out_loss) {
  double s = 0.0;
  for (int i = threadIdx.x; i < NBLK_B; i += 256) s += partial[i];
#pragma unroll
  for (int off = 32; off >= 1; off >>= 1) s += __shfl_down(s, off, 64);
  __shared__ double sh[4];
  int wv = threadIdx.x >> 6, lane = threadIdx.x & 63;
  if (lane == 0) sh[wv] = s;
  __syncthreads();
  if (threadIdx.x == 0) {
    double tot = sh[0] + sh[1] + sh[2] + sh[3];
    double mse = tot / (double)((size_t)N_TOT * C_DIM);
    *out_loss = (float)(1.75 * mse);  // 0.75*q_latent + e_latent, both == mse
  }
}

// ---------------------------------------------------------------------------
extern "C" void kernel_launch(void* const* d_in, const int* in_sizes, int n_in,
                              void* d_out, int out_size, void* d_ws, size_t ws_size,
                              hipStream_t stream) {
  const float* ze = (const float*)d_in[0];
  const float* cb = (const float*)d_in[1];

  float* out = (float*)d_out;
  float* zq = out;                                   // [N*C]
  float* out_loss = out + (size_t)N_TOT * C_DIM;     // [1]
  float* idx_f = out_loss + 1;                       // [N]

  float* cbsq = (float*)d_ws;                             // 4 KB @0
  ushort* cbh = (ushort*)((char*)d_ws + 8192);            // 256 KB
  ushort* cand = (ushort*)((char*)d_ws + 270336);         // 1 MB
  double* partial = (double*)((char*)d_ws + 1318912);     // 128 KB

  cbsq_kernel<<<K_CB / 4, 256, 0, stream>>>(cb, cbsq);
  cbconv_kernel<<<K_CB * C_DIM / 4 / 256, 256, 0, stream>>>(cb, cbh);
  dist_mfma_kernel<<<N_TOT / BN, 256, 0, stream>>>(ze, cbh, cbsq, cand);
  rescore_kernel<<<NBLK_B, 256, 0, stream>>>(ze, cb, cbsq, cand, zq, idx_f, partial);
  finalize_kernel<<<1, 256, 0, stream>>>(partial, out_loss);
}